// Round 1
// baseline (2569.982 us; speedup 1.0000x reference)
//
#include <hip/hip_runtime.h>

#define TPB 256

// ---------------------------------------------------------------------------
// Dense layer helpers: per-thread tile = 1 row x 4 (or 2) cols, K innermost.
// Input rows come from LDS (broadcast across col-threads), weights from
// global (coalesced float4/float2; hot in L1/L2), bias from global.
// ---------------------------------------------------------------------------

template<int K, int C, int LDIN, bool RELU, bool EXTRA>
__device__ __forceinline__ void dense4(int R, const float* s_in,
    const float* __restrict__ W, const float* __restrict__ bias,
    const float* s_extra, float* s_out, int tid)
{
    constexpr int CT = C / 4;
    for (int u = tid; u < R * CT; u += TPB) {
        const int n = u / CT;
        const int j = 4 * (u - n * CT);
        float4 acc = *(const float4*)(bias + j);
        if (EXTRA) {
            const float4 e = *(const float4*)(s_extra + j);
            acc.x += e.x; acc.y += e.y; acc.z += e.z; acc.w += e.w;
        }
        const float* ip = s_in + n * LDIN;
        const float* __restrict__ wp = W + j;
        #pragma unroll 8
        for (int k = 0; k < K; ++k) {
            const float x = ip[k];
            const float4 w = *(const float4*)(wp + k * C);
            acc.x = fmaf(x, w.x, acc.x);
            acc.y = fmaf(x, w.y, acc.y);
            acc.z = fmaf(x, w.z, acc.z);
            acc.w = fmaf(x, w.w, acc.w);
        }
        if (RELU) {
            acc.x = fmaxf(acc.x, 0.f); acc.y = fmaxf(acc.y, 0.f);
            acc.z = fmaxf(acc.z, 0.f); acc.w = fmaxf(acc.w, 0.f);
        }
        *(float4*)(s_out + n * C + j) = acc;
    }
}

template<int K, int C, int LDIN, bool RELU>
__device__ __forceinline__ void dense2(int R, const float* s_in,
    const float* __restrict__ W, const float* __restrict__ bias,
    float* s_out, int tid)
{
    constexpr int CT = C / 2;
    for (int u = tid; u < R * CT; u += TPB) {
        const int n = u / CT;
        const int j = 2 * (u - n * CT);
        float2 acc = *(const float2*)(bias + j);
        const float* ip = s_in + n * LDIN;
        const float* __restrict__ wp = W + j;
        #pragma unroll 8
        for (int k = 0; k < K; ++k) {
            const float x = ip[k];
            const float2 w = *(const float2*)(wp + k * C);
            acc.x = fmaf(x, w.x, acc.x);
            acc.y = fmaf(x, w.y, acc.y);
        }
        if (RELU) { acc.x = fmaxf(acc.x, 0.f); acc.y = fmaxf(acc.y, 0.f); }
        *(float2*)(s_out + n * C + j) = acc;
    }
}

// ---------------------------------------------------------------------------
// Kernel 1: one block per batch element. Everything through the attention
// pooling, entirely in LDS. Writes joint = [self_state(6), weighted(50)].
// ---------------------------------------------------------------------------
__global__ __launch_bounds__(TPB) void k_main(
    const float* __restrict__ state,
    const float* __restrict__ m1w0, const float* __restrict__ m1b0,
    const float* __restrict__ m1w1, const float* __restrict__ m1b1,
    const float* __restrict__ m2w0, const float* __restrict__ m2b0,
    const float* __restrict__ m2w1, const float* __restrict__ m2b1,
    const float* __restrict__ aw0,  const float* __restrict__ ab0,
    const float* __restrict__ aw1,  const float* __restrict__ ab1,
    const float* __restrict__ aw2,  const float* __restrict__ ab2,
    float* __restrict__ joint)
{
    __shared__ __align__(16) float s_x[20 * 13];     // state rows
    __shared__ __align__(16) float s_buf1[20 * 150]; // h1, then fh, then a1
    __shared__ __align__(16) float s_h[20 * 100];
    __shared__ __align__(16) float s_a2[20 * 100];
    __shared__ __align__(16) float s_f[20 * 50];
    __shared__ __align__(16) float s_g[100];
    __shared__ __align__(16) float s_gp[100];
    __shared__ float s_logit[20];

    const int tid = threadIdx.x;
    const int b = blockIdx.x;
    const float* xg = state + (size_t)b * 260;

    for (int i = tid; i < 260; i += TPB) s_x[i] = xg[i];
    __syncthreads();

    // P1: h1[20][150] = relu(x @ m1w0 + m1b0)   (K=13, C=150 -> float2)
    for (int u = tid; u < 20 * 75; u += TPB) {
        const int n = u / 75;
        const int j = 2 * (u - n * 75);
        float2 acc = *(const float2*)(m1b0 + j);
        const float* ip = s_x + n * 13;
        const float* __restrict__ wp = m1w0 + j;
        #pragma unroll
        for (int k = 0; k < 13; ++k) {
            const float x = ip[k];
            const float2 w = *(const float2*)(wp + k * 150);
            acc.x = fmaf(x, w.x, acc.x);
            acc.y = fmaf(x, w.y, acc.y);
        }
        acc.x = fmaxf(acc.x, 0.f); acc.y = fmaxf(acc.y, 0.f);
        *(float2*)(s_buf1 + n * 150 + j) = acc;
    }
    __syncthreads();

    // P2: h[20][100] = relu(h1 @ m1w1 + m1b1)
    dense4<150, 100, 150, true, false>(20, s_buf1, m1w1, m1b1, nullptr, s_h, tid);
    __syncthreads();

    // P3: fh[20][100] = relu(h @ m2w0 + m2b0)   (into s_buf1, h1 dead)
    dense4<100, 100, 100, true, false>(20, s_h, m2w0, m2b0, nullptr, s_buf1, tid);
    __syncthreads();

    // P3b: f[20][50] = fh @ m2w1 + m2b1   (no relu)
    dense2<100, 50, 100, false>(20, s_buf1, m2w1, m2b1, s_f, tid);
    __syncthreads();

    // P4a: g = mean(h, axis=rows)
    if (tid < 100) {
        float s = 0.f;
        #pragma unroll
        for (int n = 0; n < 20; ++n) s += s_h[n * 100 + tid];
        s_g[tid] = s * (1.0f / 20.0f);
    }
    __syncthreads();

    // P4b: gp[j] = sum_k g[k] * aw0[100+k][j]  (the broadcast-g half of att_in)
    if (tid < 100) {
        float acc = 0.f;
        #pragma unroll 10
        for (int k = 0; k < 100; ++k)
            acc = fmaf(s_g[k], aw0[(100 + k) * 100 + tid], acc);
        s_gp[tid] = acc;
    }
    __syncthreads();

    // P5: a1[20][100] = relu(h @ aw0[:100] + gp + ab0)   (into s_buf1, fh dead)
    dense4<100, 100, 100, true, true>(20, s_h, aw0, ab0, s_gp, s_buf1, tid);
    __syncthreads();

    // P6: a2[20][100] = relu(a1 @ aw1 + ab1)
    dense4<100, 100, 100, true, false>(20, s_buf1, aw1, ab1, nullptr, s_a2, tid);
    __syncthreads();

    // P7: logits[n] = a2[n] . aw2 + ab2
    if (tid < 20) {
        float acc = ab2[0];
        #pragma unroll 10
        for (int k = 0; k < 100; ++k)
            acc = fmaf(s_a2[tid * 100 + k], aw2[k], acc);
        s_logit[tid] = acc;
    }
    __syncthreads();

    // P8: weighted[j] = sum_n f[n][j]*logit[n]; joint = [self_state, weighted]
    if (tid < 50) {
        float acc = 0.f;
        #pragma unroll
        for (int n = 0; n < 20; ++n)
            acc = fmaf(s_f[n * 50 + tid], s_logit[n], acc);
        joint[(size_t)b * 56 + 6 + tid] = acc;
    } else if (tid < 56) {
        joint[(size_t)b * 56 + (tid - 50)] = s_x[tid - 50];
    }
}

// ---------------------------------------------------------------------------
// Kernel 2: head MLP, 8 batch rows per block.
// v = relu(joint@w0+b0); relu(@w1+b1); relu(@w2+b2); @w3+b3 -> out[b]
// ---------------------------------------------------------------------------
__global__ __launch_bounds__(TPB) void k_head(
    const float* __restrict__ joint,
    const float* __restrict__ m3w0, const float* __restrict__ m3b0,
    const float* __restrict__ m3w1, const float* __restrict__ m3b1,
    const float* __restrict__ m3w2, const float* __restrict__ m3b2,
    const float* __restrict__ m3w3, const float* __restrict__ m3b3,
    float* __restrict__ out)
{
    constexpr int RB = 8;
    __shared__ __align__(16) float s_j[RB * 56];
    __shared__ __align__(16) float s_v1[RB * 150];
    __shared__ __align__(16) float s_v2[RB * 100];
    __shared__ __align__(16) float s_v3[RB * 100];

    const int tid = threadIdx.x;
    const size_t r0 = (size_t)blockIdx.x * RB;

    for (int i = tid; i < RB * 56; i += TPB) s_j[i] = joint[r0 * 56 + i];
    __syncthreads();

    // m3-0: K=56, C=150 (float2)
    dense2<56, 150, 56, true>(RB, s_j, m3w0, m3b0, s_v1, tid);
    __syncthreads();

    // m3-1: K=150, C=100
    dense4<150, 100, 150, true, false>(RB, s_v1, m3w1, m3b1, nullptr, s_v2, tid);
    __syncthreads();

    // m3-2: K=100, C=100
    dense4<100, 100, 100, true, false>(RB, s_v2, m3w2, m3b2, nullptr, s_v3, tid);
    __syncthreads();

    // m3-3: out[r] = v3[r] . m3w3 + m3b3  (32 lanes per row)
    {
        const int r = tid >> 5;
        const int lane = tid & 31;
        float acc = 0.f;
        for (int k = lane; k < 100; k += 32)
            acc = fmaf(s_v3[r * 100 + k], m3w3[k], acc);
        #pragma unroll
        for (int off = 16; off > 0; off >>= 1)
            acc += __shfl_down(acc, off, 32);
        if (lane == 0) out[r0 + r] = acc + m3b3[0];
    }
}

extern "C" void kernel_launch(void* const* d_in, const int* in_sizes, int n_in,
                              void* d_out, int out_size, void* d_ws, size_t ws_size,
                              hipStream_t stream) {
    const float* state = (const float*)d_in[0];
    const float* m1w0 = (const float*)d_in[1];
    const float* m1b0 = (const float*)d_in[2];
    const float* m1w1 = (const float*)d_in[3];
    const float* m1b1 = (const float*)d_in[4];
    const float* m2w0 = (const float*)d_in[5];
    const float* m2b0 = (const float*)d_in[6];
    const float* m2w1 = (const float*)d_in[7];
    const float* m2b1 = (const float*)d_in[8];
    const float* aw0  = (const float*)d_in[9];
    const float* ab0  = (const float*)d_in[10];
    const float* aw1  = (const float*)d_in[11];
    const float* ab1  = (const float*)d_in[12];
    const float* aw2  = (const float*)d_in[13];
    const float* ab2  = (const float*)d_in[14];
    const float* m3w0 = (const float*)d_in[15];
    const float* m3b0 = (const float*)d_in[16];
    const float* m3w1 = (const float*)d_in[17];
    const float* m3b1 = (const float*)d_in[18];
    const float* m3w2 = (const float*)d_in[19];
    const float* m3b2 = (const float*)d_in[20];
    const float* m3w3 = (const float*)d_in[21];
    const float* m3b3 = (const float*)d_in[22];

    const int B = 16384;
    float* joint = (float*)d_ws;   // B*56 floats = 3.67 MB

    k_main<<<B, TPB, 0, stream>>>(state,
        m1w0, m1b0, m1w1, m1b1, m2w0, m2b0, m2w1, m2b1,
        aw0, ab0, aw1, ab1, aw2, ab2, joint);

    k_head<<<B / 8, TPB, 0, stream>>>(joint,
        m3w0, m3b0, m3w1, m3b1, m3w2, m3b2, m3w3, m3b3,
        (float*)d_out);
}

// Round 2
// 1710.018 us; speedup vs baseline: 1.5029x; 1.5029x over previous
//
#include <hip/hip_runtime.h>

// Lane = batch-row design. TPB=64 (1 wave/block).
// k_main: 3 elements (60 rows) per block, lanes 60-63 idle-but-harmless.
// Weights are wave-uniform -> scalar loads (s_load) broadcast via VALU SGPR
// operand. Activations: accumulators in VGPRs (statically indexed);
// layer inputs round-trip through a small LDS chunk buffer (pair-major,
// ds_read_b64) to allow dynamic-K loops: 100 FMAs per LDS read.

#define NELEM 16384
#define NROWS (NELEM * 20)

// ---- LDS chunk helpers: pair-major layout [kk][lane*2 + i], 128 dwords/row --

template<int K>
__device__ __forceinline__ void stage_chunk(float* sb, const float* v, int lane) {
    #pragma unroll
    for (int kk = 0; kk < K / 2; ++kk)
        *(float2*)(sb + kk * 128 + 2 * lane) = make_float2(v[2 * kk], v[2 * kk + 1]);
    if (K & 1) sb[(K / 2) * 128 + 2 * lane] = v[K - 1];
}

// acc[CH] += sum_k sb[k][lane] * W[k*ldw + c]   (W pre-offset to kbase,cbase)
template<int K, int CH>
__device__ __forceinline__ void accum_chunk(float* acc, const float* __restrict__ W,
                                            int ldw, const float* sb, int lane) {
    constexpr int PAIRS = K / 2;
    float2 xv = *(const float2*)(sb + 2 * lane);
    #pragma unroll 1
    for (int kk = 0; kk < PAIRS; ++kk) {
        const int kn = (kk + 1 < PAIRS) ? kk + 1 : kk;       // uniform, branchless
        const float2 xn = *(const float2*)(sb + kn * 128 + 2 * lane);
        const float* __restrict__ w0 = W + (2 * kk) * ldw;
        #pragma unroll
        for (int c = 0; c < CH; ++c) acc[c] = fmaf(xv.x, w0[c], acc[c]);
        #pragma unroll
        for (int c = 0; c < CH; ++c) acc[c] = fmaf(xv.y, w0[ldw + c], acc[c]);
        xv = xn;
    }
    if (K & 1) {
        const float xs = sb[PAIRS * 128 + 2 * lane];
        const float* __restrict__ w0 = W + (K - 1) * ldw;
        #pragma unroll
        for (int c = 0; c < CH; ++c) acc[c] = fmaf(xs, w0[c], acc[c]);
    }
}

// ---------------------------------------------------------------------------
// k_main: per block: 3 elements. Produces wbuf[e][50] = "weighted".
// ---------------------------------------------------------------------------
__global__ __launch_bounds__(64, 2) void k_main(
    const float* __restrict__ state,
    const float* __restrict__ m1w0, const float* __restrict__ m1b0,
    const float* __restrict__ m1w1, const float* __restrict__ m1b1,
    const float* __restrict__ m2w0, const float* __restrict__ m2b0,
    const float* __restrict__ m2w1, const float* __restrict__ m2b1,
    const float* __restrict__ aw0,  const float* __restrict__ ab0,
    const float* __restrict__ aw1,  const float* __restrict__ ab1,
    const float* __restrict__ aw2,  const float* __restrict__ ab2,
    float* __restrict__ wbuf)
{
    __shared__ __align__(16) float sbuf[13 * 128];   // K-chunk stream buffer (25 k's)
    __shared__ __align__(16) float buf2[50 * 64];    // xs early, then f park
    __shared__ float gbuf[100 * 4];                  // g^T[c][e]
    __shared__ float gpbuf[100 * 4];                 // gp^T[c][e]
    __shared__ float lbuf[64];                       // logits per row

    const int lane = threadIdx.x;
    const int b = blockIdx.x;
    const int row = 60 * b + lane;                   // lanes 0..59 = real rows
    const int crow = row < NROWS ? row : NROWS - 1;  // clamp tail (finite data)

    // ---- stage x[13] (pair-major into buf2 region) ----
    {
        float xv[13];
        #pragma unroll
        for (int d = 0; d < 13; ++d) xv[d] = state[(size_t)crow * 13 + d];
        stage_chunk<13>(buf2, xv, lane);
    }
    __syncthreads();

    // ---- h = relu(relu(x@m1w0+m1b0) @ m1w1 + m1b1), h1 in 6 chunks of 25 ----
    float h[100];
    #pragma unroll
    for (int c = 0; c < 100; ++c) h[c] = m1b1[c];
    #pragma unroll
    for (int kc = 0; kc < 6; ++kc) {
        float t[25];
        #pragma unroll
        for (int j = 0; j < 25; ++j) t[j] = m1b0[kc * 25 + j];
        accum_chunk<13, 25>(t, m1w0 + kc * 25, 150, buf2, lane);
        #pragma unroll
        for (int j = 0; j < 25; ++j) t[j] = fmaxf(t[j], 0.f);
        __syncthreads();
        stage_chunk<25>(sbuf, t, lane);
        __syncthreads();
        accum_chunk<25, 50>(h,      m1w1 + (kc * 25) * 100,      100, sbuf, lane);
        accum_chunk<25, 50>(h + 50, m1w1 + (kc * 25) * 100 + 50, 100, sbuf, lane);
    }
    #pragma unroll
    for (int c = 0; c < 100; ++c) h[c] = fmaxf(h[c], 0.f);

    // ---- fh = relu(h @ m2w0 + m2b0) ----
    float fh[100];
    #pragma unroll
    for (int c = 0; c < 100; ++c) fh[c] = m2b0[c];
    #pragma unroll
    for (int kc = 0; kc < 4; ++kc) {
        __syncthreads();
        stage_chunk<25>(sbuf, h + kc * 25, lane);
        __syncthreads();
        accum_chunk<25, 50>(fh,      m2w0 + (kc * 25) * 100,      100, sbuf, lane);
        accum_chunk<25, 50>(fh + 50, m2w0 + (kc * 25) * 100 + 50, 100, sbuf, lane);
    }
    #pragma unroll
    for (int c = 0; c < 100; ++c) fh[c] = fmaxf(fh[c], 0.f);

    // ---- f = fh @ m2w1 + m2b1 (no relu); park in buf2 as f[j][lane] ----
    #pragma unroll
    for (int half = 0; half < 2; ++half) {
        float fa[25];
        #pragma unroll
        for (int j = 0; j < 25; ++j) fa[j] = m2b1[half * 25 + j];
        #pragma unroll
        for (int kc = 0; kc < 4; ++kc) {
            __syncthreads();
            stage_chunk<25>(sbuf, fh + kc * 25, lane);
            __syncthreads();
            accum_chunk<25, 25>(fa, m2w1 + (kc * 25) * 50 + half * 25, 50, sbuf, lane);
        }
        __syncthreads();   // buf2: xs region dead after phase above / prior half writes done
        #pragma unroll
        for (int j = 0; j < 25; ++j) buf2[(half * 25 + j) * 64 + lane] = fa[j];
    }

    // ---- a1 = relu(h @ aw0[:100] + g @ aw0[100:] + ab0); g during staging ----
    float a1[100];
    #pragma unroll
    for (int c = 0; c < 100; ++c) a1[c] = ab0[c];
    #pragma unroll
    for (int kc = 0; kc < 4; ++kc) {
        __syncthreads();
        stage_chunk<25>(sbuf, h + kc * 25, lane);
        __syncthreads();
        // g for cols of this chunk: 75 tasks = 3 elems x 25 cols
        for (int u = lane; u < 75; u += 64) {
            const int e = u / 25, c = u % 25;
            float s = 0.f;
            #pragma unroll
            for (int n = 0; n < 20; ++n)
                s += sbuf[(c >> 1) * 128 + 2 * (e * 20 + n) + (c & 1)];
            gbuf[(kc * 25 + c) * 4 + e] = s * 0.05f;
        }
        accum_chunk<25, 50>(a1,      aw0 + (kc * 25) * 100,      100, sbuf, lane);
        accum_chunk<25, 50>(a1 + 50, aw0 + (kc * 25) * 100 + 50, 100, sbuf, lane);
    }
    __syncthreads();
    // gp[e][c] = sum_k g[e][k] * aw0[100+k][c]
    for (int u = lane; u < 300; u += 64) {
        const int e = u / 100, c = u % 100;
        float s = 0.f;
        for (int k = 0; k < 100; ++k)
            s = fmaf(gbuf[k * 4 + e], aw0[(100 + k) * 100 + c], s);
        gpbuf[c * 4 + e] = s;
    }
    __syncthreads();
    {
        const int el = lane / 20;   // 0..3 (3 = idle lanes, reads garbage, harmless)
        #pragma unroll
        for (int c = 0; c < 100; ++c) a1[c] = fmaxf(a1[c] + gpbuf[c * 4 + el], 0.f);
    }

    // ---- a2 = relu(a1 @ aw1 + ab1) ----
    float a2[100];
    #pragma unroll
    for (int c = 0; c < 100; ++c) a2[c] = ab1[c];
    #pragma unroll
    for (int kc = 0; kc < 4; ++kc) {
        __syncthreads();
        stage_chunk<25>(sbuf, a1 + kc * 25, lane);
        __syncthreads();
        accum_chunk<25, 50>(a2,      aw1 + (kc * 25) * 100,      100, sbuf, lane);
        accum_chunk<25, 50>(a2 + 50, aw1 + (kc * 25) * 100 + 50, 100, sbuf, lane);
    }

    // ---- logit per row ----
    {
        float lg = ab2[0];
        #pragma unroll
        for (int c = 0; c < 100; ++c) lg = fmaf(fmaxf(a2[c], 0.f), aw2[c], lg);
        lbuf[lane] = lg;
    }
    __syncthreads();

    // ---- weighted[e][j] = sum_n f[e,n][j] * logit[e,n] ----
    for (int u = lane; u < 150; u += 64) {
        const int e = u / 50, j = u % 50;
        float s = 0.f;
        #pragma unroll
        for (int n = 0; n < 20; ++n)
            s = fmaf(buf2[j * 64 + e * 20 + n], lbuf[e * 20 + n], s);
        const int eg = 3 * b + e;
        if (eg < NELEM) wbuf[(size_t)eg * 50 + j] = s;
    }
}

// ---------------------------------------------------------------------------
// k_head: lane = element. joint = [state[e,0,:6], wbuf[e,:50]] -> 4-layer MLP.
// ---------------------------------------------------------------------------
__global__ __launch_bounds__(64, 2) void k_head(
    const float* __restrict__ state, const float* __restrict__ wbuf,
    const float* __restrict__ m3w0, const float* __restrict__ m3b0,
    const float* __restrict__ m3w1, const float* __restrict__ m3b1,
    const float* __restrict__ m3w2, const float* __restrict__ m3b2,
    const float* __restrict__ m3w3, const float* __restrict__ m3b3,
    float* __restrict__ out)
{
    __shared__ __align__(16) float sj[28 * 128];     // joint, pair-major (56 k's)
    __shared__ __align__(16) float sb2[13 * 128];    // chunk buffer

    const int lane = threadIdx.x;
    const int e = blockIdx.x * 64 + lane;            // exact: 16384 = 256*64

    {
        float jv[56];
        #pragma unroll
        for (int d = 0; d < 6; ++d) jv[d] = state[(size_t)e * 260 + d];
        #pragma unroll
        for (int j = 0; j < 50; ++j) jv[6 + j] = wbuf[(size_t)e * 50 + j];
        stage_chunk<56>(sj, jv, lane);
    }
    __syncthreads();

    // v2 = relu(relu(joint@m3w0+b0) @ m3w1 + b1), v1 in 6 chunks of 25
    float v2[100];
    #pragma unroll
    for (int c = 0; c < 100; ++c) v2[c] = m3b1[c];
    #pragma unroll
    for (int kc = 0; kc < 6; ++kc) {
        float t[25];
        #pragma unroll
        for (int j = 0; j < 25; ++j) t[j] = m3b0[kc * 25 + j];
        accum_chunk<56, 25>(t, m3w0 + kc * 25, 150, sj, lane);
        #pragma unroll
        for (int j = 0; j < 25; ++j) t[j] = fmaxf(t[j], 0.f);
        __syncthreads();
        stage_chunk<25>(sb2, t, lane);
        __syncthreads();
        accum_chunk<25, 50>(v2,      m3w1 + (kc * 25) * 100,      100, sb2, lane);
        accum_chunk<25, 50>(v2 + 50, m3w1 + (kc * 25) * 100 + 50, 100, sb2, lane);
    }
    #pragma unroll
    for (int c = 0; c < 100; ++c) v2[c] = fmaxf(v2[c], 0.f);

    // v3 = relu(v2 @ m3w2 + b2)
    float v3[100];
    #pragma unroll
    for (int c = 0; c < 100; ++c) v3[c] = m3b2[c];
    #pragma unroll
    for (int kc = 0; kc < 4; ++kc) {
        __syncthreads();
        stage_chunk<25>(sb2, v2 + kc * 25, lane);
        __syncthreads();
        accum_chunk<25, 50>(v3,      m3w2 + (kc * 25) * 100,      100, sb2, lane);
        accum_chunk<25, 50>(v3 + 50, m3w2 + (kc * 25) * 100 + 50, 100, sb2, lane);
    }

    // v4 = v3 @ m3w3 + b3
    {
        float acc = m3b3[0];
        #pragma unroll
        for (int c = 0; c < 100; ++c) acc = fmaf(fmaxf(v3[c], 0.f), m3w3[c], acc);
        out[e] = acc;
    }
}

extern "C" void kernel_launch(void* const* d_in, const int* in_sizes, int n_in,
                              void* d_out, int out_size, void* d_ws, size_t ws_size,
                              hipStream_t stream) {
    const float* state = (const float*)d_in[0];
    const float* m1w0 = (const float*)d_in[1];
    const float* m1b0 = (const float*)d_in[2];
    const float* m1w1 = (const float*)d_in[3];
    const float* m1b1 = (const float*)d_in[4];
    const float* m2w0 = (const float*)d_in[5];
    const float* m2b0 = (const float*)d_in[6];
    const float* m2w1 = (const float*)d_in[7];
    const float* m2b1 = (const float*)d_in[8];
    const float* aw0  = (const float*)d_in[9];
    const float* ab0  = (const float*)d_in[10];
    const float* aw1  = (const float*)d_in[11];
    const float* ab1  = (const float*)d_in[12];
    const float* aw2  = (const float*)d_in[13];
    const float* ab2  = (const float*)d_in[14];
    const float* m3w0 = (const float*)d_in[15];
    const float* m3b0 = (const float*)d_in[16];
    const float* m3w1 = (const float*)d_in[17];
    const float* m3b1 = (const float*)d_in[18];
    const float* m3w2 = (const float*)d_in[19];
    const float* m3b2 = (const float*)d_in[20];
    const float* m3w3 = (const float*)d_in[21];
    const float* m3b3 = (const float*)d_in[22];

    float* wbuf = (float*)d_ws;   // 16384*50 floats = 3.28 MB

    const int nblk = (NELEM + 2) / 3;   // 5462
    k_main<<<nblk, 64, 0, stream>>>(state,
        m1w0, m1b0, m1w1, m1b1, m2w0, m2b0, m2w1, m2b1,
        aw0, ab0, aw1, ab1, aw2, ab2, wbuf);

    k_head<<<NELEM / 64, 64, 0, stream>>>(state, wbuf,
        m3w0, m3b0, m3w1, m3b1, m3w2, m3b2, m3w3, m3b3,
        (float*)d_out);
}

// Round 3
// 293.529 us; speedup vs baseline: 8.7555x; 5.8257x over previous
//
#include <hip/hip_runtime.h>

typedef _Float16 half_t;
typedef _Float16 half8 __attribute__((ext_vector_type(8)));
typedef float f32x4 __attribute__((ext_vector_type(4)));

#define NELEM 16384

// ---------------------------------------------------------------------------
// Generic fused dense layer via 16x16x32 f16 MFMA.
//   A (activations) : LDS, fp16, row-major, stride sA halves (16B-aligned).
//   B (weights)     : global, pre-swizzled fragments [split][ks][nt][lane][8],
//                     split 0 = hi(fp16(w)), split 1 = lo(fp16(w - hi)).
//   Verified gfx950 layouts: A[m=lane&15][k=quad*8+j], B[k][n=lane&15],
//                            D[row=quad*4+r][col=lane&15].
// EPI: 0 = fp16 store (relu opt), 1 = fp32 store col<C (f), 2 = logits col0,
//      3 = gp store rows 0..3 (quad 0).
// INIT: 0 = bias only, 1 = bias + gp[row/20][col] (a1 layer).
// NTZ >= NT: tiles beyond NT write zeros (K-padding hygiene for buffer reuse).
// ---------------------------------------------------------------------------
template<int KS, int EPI, int INIT>
__device__ __forceinline__ void dense_mfma(
    const half_t* inA, int sA, void* outP, int sO,
    const half_t* __restrict__ wf, const float* __restrict__ bias,
    const float* gp, float* lbuf, float extra,
    int MT, int NT, int NTZ, int C, bool relu, int tid)
{
    const int lane = tid & 63, wave = tid >> 6;
    const int m = lane & 15, quad = lane >> 4;
    for (int nt = wave; nt < NTZ; nt += 4) {
        const int col = nt * 16 + m;
        const bool live = nt < NT;
        half8 bh[KS], bl[KS];
        float bv = 0.f;
        if (live) {
            #pragma unroll
            for (int ks = 0; ks < KS; ++ks) {
                bh[ks] = *(const half8*)(wf + ((size_t)((0*KS+ks)*NT + nt)*64 + lane)*8);
                bl[ks] = *(const half8*)(wf + ((size_t)((1*KS+ks)*NT + nt)*64 + lane)*8);
            }
            if (bias && col < C) bv = bias[col];
        }
        for (int mt0 = 0; mt0 < MT; mt0 += 2) {
            const bool two = (mt0 + 1) < MT;
            f32x4 acc0 = {0.f,0.f,0.f,0.f}, acc1 = {0.f,0.f,0.f,0.f};
            if (live) {
                const half_t* ap0 = inA + (mt0*16 + m)*sA + quad*8;
                const half_t* ap1 = ap0 + 16*sA;
                half8 a0[KS], a1[KS];
                #pragma unroll
                for (int ks = 0; ks < KS; ++ks) {
                    a0[ks] = *(const half8*)(ap0 + ks*32);
                    if (two) a1[ks] = *(const half8*)(ap1 + ks*32);
                }
                #pragma unroll
                for (int ks = 0; ks < KS; ++ks) {
                    acc0 = __builtin_amdgcn_mfma_f32_16x16x32_f16(a0[ks], bh[ks], acc0, 0,0,0);
                    if (two) acc1 = __builtin_amdgcn_mfma_f32_16x16x32_f16(a1[ks], bh[ks], acc1, 0,0,0);
                    acc0 = __builtin_amdgcn_mfma_f32_16x16x32_f16(a0[ks], bl[ks], acc0, 0,0,0);
                    if (two) acc1 = __builtin_amdgcn_mfma_f32_16x16x32_f16(a1[ks], bl[ks], acc1, 0,0,0);
                }
            }
            #pragma unroll
            for (int p = 0; p < 2; ++p) {
                if (p == 1 && !two) break;
                const int mt = mt0 + p;
                f32x4 acc = p ? acc1 : acc0;
                #pragma unroll
                for (int r = 0; r < 4; ++r) {
                    const int row = mt*16 + quad*4 + r;
                    float v = acc[r] + bv;
                    if (INIT == 1) { if (live) v += gp[(row/20)*112 + col]; }
                    if (relu) v = fmaxf(v, 0.f);
                    if (EPI == 0) {
                        ((half_t*)outP)[row*sO + col] = (half_t)v;
                    } else if (EPI == 1) {
                        if (col < C) ((float*)outP)[row*sO + col] = v;
                    } else if (EPI == 2) {
                        if (m == 0) lbuf[row] = acc[r] + extra;
                    } else {
                        if (quad == 0) ((float*)outP)[r*sO + col] = acc[r];
                    }
                }
            }
        }
    }
}

// ---------------------------------------------------------------------------
// Prep: build split-fp16 weight fragments in ws.
// ---------------------------------------------------------------------------
struct PrepDesc { const float* w; half_t* out; int K, C, KS, NT, toff; };
struct PrepArgs { PrepDesc d[11]; };

__global__ __launch_bounds__(64) void k_prep(PrepArgs a) {
    const int blk = blockIdx.x, lane = threadIdx.x;
    int li = 0;
    #pragma unroll
    for (int i = 1; i < 11; ++i) if (blk >= a.d[i].toff) li = i;
    const PrepDesc d = a.d[li];
    const int t = blk - d.toff;
    const int kn = d.KS * d.NT;
    const int split = t / kn;
    const int rem = t - split * kn;
    const int ks = rem / d.NT, nt = rem - (rem / d.NT) * d.NT;
    const int c = nt*16 + (lane & 15);
    half_t* o = d.out + ((size_t)(split*d.KS + ks)*d.NT + nt)*512 + lane*8;
    #pragma unroll
    for (int j = 0; j < 8; ++j) {
        const int k = ks*32 + (lane >> 4)*8 + j;
        float v = (k < d.K && c < d.C) ? d.w[(size_t)k*d.C + c] : 0.f;
        half_t hi = (half_t)v;
        half_t lo = (half_t)(v - (float)hi);
        o[j] = split ? lo : hi;
    }
}

// ---------------------------------------------------------------------------
// Main: 4 elements (80 rows) per block. Through attention; writes joint[e][56].
// ---------------------------------------------------------------------------
__global__ __launch_bounds__(256) void k_main(
    const float* __restrict__ state,
    const half_t* __restrict__ wfrag,
    const float* __restrict__ m1b0, const float* __restrict__ m1b1,
    const float* __restrict__ m2b0, const float* __restrict__ m2b1,
    const float* __restrict__ ab0, const float* __restrict__ ab1,
    const float* __restrict__ ab2,
    float* __restrict__ joint)
{
    __shared__ __align__(16) half_t bufA[80*168];
    __shared__ __align__(16) half_t bufB[80*168];
    __shared__ __align__(16) float  fbuf[80*56];
    __shared__ __align__(16) half_t gbuf[16*136];
    __shared__ __align__(16) float  gpbuf[4*112];
    __shared__ float lbuf[80];

    const int tid = threadIdx.x;
    const int blk = blockIdx.x;

    for (int i = tid; i < 80*168; i += 256) bufA[i] = (half_t)0.f;
    for (int i = tid; i < 16*136; i += 256) gbuf[i] = (half_t)0.f;
    __syncthreads();
    for (int u = tid; u < 80*13; u += 256) {
        const int r = u / 13, d = u - r*13;
        bufA[r*168 + d] = (half_t)state[(size_t)(blk*80 + r)*13 + d];
    }
    __syncthreads();

    const half_t* wfL0 = wfrag;
    const half_t* wfL1 = wfL0 + 10240;
    const half_t* wfL2 = wfL1 + 35840;
    const half_t* wfL3 = wfL2 + 28672;
    const half_t* wfL4 = wfL3 + 16384;
    const half_t* wfL5 = wfL4 + 28672;
    const half_t* wfL6 = wfL5 + 28672;
    const half_t* wfL7 = wfL6 + 28672;

    // h1 = relu(x @ m1w0 + b)
    dense_mfma<1,0,0>(bufA,168, bufB,168, wfL0, m1b0, nullptr,nullptr,0.f, 5,10,10,150,true, tid);
    __syncthreads();
    // h = relu(h1 @ m1w1 + b)
    dense_mfma<5,0,0>(bufB,168, bufA,168, wfL1, m1b1, nullptr,nullptr,0.f, 5,7,8,100,true, tid);
    __syncthreads();
    // fh = relu(h @ m2w0 + b);  g = mean_n h
    dense_mfma<4,0,0>(bufA,168, bufB,168, wfL2, m2b0, nullptr,nullptr,0.f, 5,7,8,100,true, tid);
    for (int u = tid; u < 400; u += 256) {
        const int e = u / 100, c = u - e*100;
        float s = 0.f;
        #pragma unroll
        for (int n = 0; n < 20; ++n) s += (float)bufA[(e*20+n)*168 + c];
        gbuf[e*136 + c] = (half_t)(s * 0.05f);
    }
    __syncthreads();
    // f = fh @ m2w1 + b (fp32);  gp = g @ aw0[100:]
    dense_mfma<4,1,0>(bufB,168, fbuf,56, wfL3, m2b1, nullptr,nullptr,0.f, 5,4,4,50,false, tid);
    dense_mfma<4,3,0>(gbuf,136, gpbuf,112, wfL5, nullptr, nullptr,nullptr,0.f, 1,7,7,100,false, tid);
    __syncthreads();
    // a1 = relu(h @ aw0[:100] + gp + ab0)
    dense_mfma<4,0,1>(bufA,168, bufB,168, wfL4, ab0, gpbuf,nullptr,0.f, 5,7,8,100,true, tid);
    __syncthreads();
    // a2 = relu(a1 @ aw1 + ab1)
    dense_mfma<4,0,0>(bufB,168, bufA,168, wfL6, ab1, nullptr,nullptr,0.f, 5,7,8,100,true, tid);
    __syncthreads();
    // logits = a2 @ aw2 + ab2
    dense_mfma<4,2,0>(bufA,168, nullptr,0, wfL7, nullptr, nullptr,lbuf,ab2[0], 5,1,1,1,false, tid);
    __syncthreads();
    // weighted + self -> joint
    for (int u = tid; u < 224; u += 256) {
        if (u < 200) {
            const int e = u / 50, j = u - e*50;
            float s = 0.f;
            #pragma unroll
            for (int n = 0; n < 20; ++n)
                s = fmaf(fbuf[(e*20+n)*56 + j], lbuf[e*20+n], s);
            joint[(size_t)(blk*4+e)*56 + 6 + j] = s;
        } else {
            const int u2 = u - 200, e = u2 / 6, d = u2 - (u2/6)*6;
            joint[(size_t)(blk*4+e)*56 + d] = state[(size_t)(blk*4+e)*260 + d];
        }
    }
}

// ---------------------------------------------------------------------------
// Head: 128 elements per block, 4-layer MLP.
// ---------------------------------------------------------------------------
__global__ __launch_bounds__(256) void k_head(
    const float* __restrict__ joint,
    const half_t* __restrict__ wfrag,
    const float* __restrict__ m3b0, const float* __restrict__ m3b1,
    const float* __restrict__ m3b2,
    const float* __restrict__ m3w3, const float* __restrict__ m3b3,
    float* __restrict__ out)
{
    __shared__ __align__(16) half_t bufJ[128*72];
    __shared__ __align__(16) half_t buf1[128*168];
    __shared__ __align__(16) half_t buf2[128*136];
    __shared__ __align__(16) half_t buf3[128*136];

    const int tid = threadIdx.x;
    const int blk = blockIdx.x;

    for (int i = tid; i < 128*72; i += 256) bufJ[i] = (half_t)0.f;
    __syncthreads();
    for (int u = tid; u < 128*56; u += 256) {
        const int r = u / 56, c = u - r*56;
        bufJ[r*72 + c] = (half_t)joint[(size_t)(blk*128 + r)*56 + c];
    }
    __syncthreads();

    const half_t* wfL8  = wfrag + 181248;
    const half_t* wfL9  = wfL8 + 20480;
    const half_t* wfL10 = wfL9 + 35840;

    dense_mfma<2,0,0>(bufJ,72, buf1,168, wfL8, m3b0, nullptr,nullptr,0.f, 8,10,10,150,true, tid);
    __syncthreads();
    dense_mfma<5,0,0>(buf1,168, buf2,136, wfL9, m3b1, nullptr,nullptr,0.f, 8,7,8,100,true, tid);
    __syncthreads();
    dense_mfma<4,0,0>(buf2,136, buf3,136, wfL10, m3b2, nullptr,nullptr,0.f, 8,7,7,100,true, tid);
    __syncthreads();
    if (tid < 128) {
        float s = m3b3[0];
        #pragma unroll 4
        for (int k = 0; k < 100; ++k)
            s = fmaf((float)buf3[tid*136 + k], m3w3[k], s);
        out[(size_t)blk*128 + tid] = s;
    }
}

extern "C" void kernel_launch(void* const* d_in, const int* in_sizes, int n_in,
                              void* d_out, int out_size, void* d_ws, size_t ws_size,
                              hipStream_t stream) {
    const float* state = (const float*)d_in[0];
    const float* m1w0 = (const float*)d_in[1];
    const float* m1b0 = (const float*)d_in[2];
    const float* m1w1 = (const float*)d_in[3];
    const float* m1b1 = (const float*)d_in[4];
    const float* m2w0 = (const float*)d_in[5];
    const float* m2b0 = (const float*)d_in[6];
    const float* m2w1 = (const float*)d_in[7];
    const float* m2b1 = (const float*)d_in[8];
    const float* aw0  = (const float*)d_in[9];
    const float* ab0  = (const float*)d_in[10];
    const float* aw1  = (const float*)d_in[11];
    const float* ab1  = (const float*)d_in[12];
    const float* aw2  = (const float*)d_in[13];
    const float* ab2  = (const float*)d_in[14];
    const float* m3w0 = (const float*)d_in[15];
    const float* m3b0 = (const float*)d_in[16];
    const float* m3w1 = (const float*)d_in[17];
    const float* m3b1 = (const float*)d_in[18];
    const float* m3w2 = (const float*)d_in[19];
    const float* m3b2 = (const float*)d_in[20];
    const float* m3w3 = (const float*)d_in[21];
    const float* m3b3 = (const float*)d_in[22];

    float* joint = (float*)d_ws;                                   // 16384*56*4 = 3.67 MB
    half_t* wfrag = (half_t*)((char*)d_ws + (size_t)NELEM*56*4);   // 532 KB of fragments

    PrepArgs pa;
    int off = 0; size_t hoff = 0; int idx = 0;
    auto add = [&](const float* w, int K, int C, int KS, int NT) {
        pa.d[idx] = PrepDesc{w, wfrag + hoff, K, C, KS, NT, off};
        off += 2*KS*NT;
        hoff += (size_t)2*KS*NT*512;
        ++idx;
    };
    add(m1w0, 13, 150, 1, 10);      // L0
    add(m1w1, 150, 100, 5, 7);      // L1
    add(m2w0, 100, 100, 4, 7);      // L2
    add(m2w1, 100, 50, 4, 4);       // L3
    add(aw0, 100, 100, 4, 7);       // L4  (rows 0..99)
    add(aw0 + 100*100, 100, 100, 4, 7); // L5 (rows 100..199)
    add(aw1, 100, 100, 4, 7);       // L6
    add(aw2, 100, 1, 4, 1);         // L7
    add(m3w0, 56, 150, 2, 10);      // L8
    add(m3w1, 150, 100, 5, 7);      // L9
    add(m3w2, 100, 100, 4, 7);      // L10

    k_prep<<<off, 64, 0, stream>>>(pa);

    k_main<<<NELEM/4, 256, 0, stream>>>(state, wfrag,
        m1b0, m1b1, m2b0, m2b1, ab0, ab1, ab2, joint);

    k_head<<<NELEM/128, 256, 0, stream>>>(joint, wfrag,
        m3b0, m3b1, m3b2, m3w3, m3b3, (float*)d_out);
}